// Round 1
// baseline (7769.711 us; speedup 1.0000x reference)
//
#include <hip/hip_runtime.h>
#include <math.h>

// RPN head, fp64-accumulation correctness anchor.
// B=32 H=64 W=64 C=512 -> feat 256 -> {9 obj, 36 reg} -> masked concat [B,H,W,45]
//
// Precision rationale: checker threshold ~1.67 (bf16-grade on values) BUT the
// keep-mask (obj>0.7 & w>10 & h>10) makes any boundary flip an error >= 10.
// fp64 accumulation matches an fp64 numpy reference to ~1e-13 => no flips.

#define Bn 32
#define Hn 64
#define Wn 64
#define Cn 512
#define Fn 256
#define TH 2
#define TW 16
#define CCn 64          // channel chunk staged per LDS pass
#define NCHUNK (Cn/CCn) // 8
#define COLS 18         // TW + 2 halo
#define CPAD 20         // row vector padded to 20 doubles (160B, 16B-aligned)
#define NPOS (TH*TW)    // 32
#define NOUT 45

__global__ __launch_bounds__(256, 1) void rpn_fp64_kernel(
    const float* __restrict__ x,
    const float* __restrict__ base_w,
    const float* __restrict__ base_b,
    const float* __restrict__ cls_w,
    const float* __restrict__ cls_b,
    const float* __restrict__ reg_w,
    const float* __restrict__ reg_b,
    float* __restrict__ out)
{
    __shared__ __align__(16) char smem_raw[65536];
    double* xs    = (double*)smem_raw;  // [4][CCn][CPAD] = 40960 B (staging phase)
    double* feats = (double*)smem_raw;  // [NPOS][Fn]     = 65536 B (epilogue phase)
    double* vals  = (double*)smem_raw;  // [NPOS][NOUT]   = 11520 B (final phase)

    const int tid = threadIdx.x;
    const int bid = blockIdx.x;
    const int wb = bid & 3;          // 4 w-tiles of 16
    const int hb = (bid >> 2) & 31;  // 32 h-tiles of 2
    const int b  = bid >> 7;         // 32 batches
    const int h0 = hb * TH, w0 = wb * TW;

    double acc0[TW], acc1[TW];
    #pragma unroll
    for (int i = 0; i < TW; i++) { acc0[i] = 0.0; acc1[i] = 0.0; }

    for (int ch = 0; ch < NCHUNK; ch++) {
        const int cbase = ch * CCn;
        __syncthreads();  // protect xs against previous iteration's readers
        // stage 4 rows x 18 cols x 64 ch, converted to double
        for (int i = tid; i < 4 * COLS * CCn; i += 256) {
            const int c   = i & (CCn - 1);
            const int col = (i / CCn) % COLS;
            const int row = i / (CCn * COLS);
            const int y  = h0 + row - 1;
            const int xw = w0 + col - 1;
            float v = 0.f;
            if ((unsigned)y < (unsigned)Hn && (unsigned)xw < (unsigned)Wn)
                v = x[(((size_t)b * Hn + y) * Wn + xw) * Cn + cbase + c];
            xs[(row * CCn + c) * CPAD + col] = (double)v;
        }
        __syncthreads();

        for (int c = 0; c < CCn; c++) {
            const int cg = cbase + c;
            #pragma unroll
            for (int ky = 0; ky < 3; ky++) {
                // output row ph uses input row ph+ky (local rows ky, ky+1)
                const double* r0 = &xs[((ky    ) * CCn + c) * CPAD];
                const double* r1 = &xs[((ky + 1) * CCn + c) * CPAD];
                double a0[COLS], a1[COLS];
                #pragma unroll
                for (int j = 0; j < COLS; j++) { a0[j] = r0[j]; a1[j] = r1[j]; }
                #pragma unroll
                for (int kx = 0; kx < 3; kx++) {
                    const double wv =
                        (double)base_w[(((size_t)(ky * 3 + kx) * Cn + cg) * Fn) + tid];
                    #pragma unroll
                    for (int p = 0; p < TW; p++) {
                        acc0[p] = fma(a0[p + kx], wv, acc0[p]);
                        acc1[p] = fma(a1[p + kx], wv, acc1[p]);
                    }
                }
            }
        }
    }

    // bias + relu, scatter feat (channel tid) for all 32 positions into LDS
    const double bias = (double)base_b[tid];
    __syncthreads();
    #pragma unroll
    for (int p = 0; p < TW; p++) {
        double f0 = acc0[p] + bias; if (f0 < 0.0) f0 = 0.0;
        double f1 = acc1[p] + bias; if (f1 < 0.0) f1 = 0.0;
        feats[(0 * TW + p) * Fn + tid] = f0;
        feats[(1 * TW + p) * Fn + tid] = f1;
    }
    __syncthreads();

    // 1x1 convs: 32 positions x 45 outputs = 1440 length-256 fp64 dots
    const int ntask = NPOS * NOUT;  // 1440
    double res[6];
    #pragma unroll
    for (int k = 0; k < 6; k++) res[k] = 0.0;
    for (int k = 0; k < 6; k++) {
        const int task = tid + k * 256;
        if (task < ntask) {
            const int p = task / NOUT, o = task % NOUT;
            const float* wsel;
            int stride;
            double s;
            if (o < 36) { wsel = reg_w + o; stride = 36; s = (double)reg_b[o]; }
            else        { wsel = cls_w + (o - 36); stride = 9; s = (double)cls_b[o - 36]; }
            const double* fp = &feats[p * Fn];
            double acc = 0.0;
            for (int t = 0; t < Fn; t++)
                acc = fma(fp[t], (double)wsel[(size_t)t * stride], acc);
            s += acc;
            if (o >= 36) s = 1.0 / (1.0 + exp(-s));  // sigmoid, double precision
            res[k] = s;
        }
    }
    __syncthreads();  // all feat reads done; reuse smem for vals
    for (int k = 0; k < 6; k++) {
        const int task = tid + k * 256;
        if (task < ntask) vals[task] = res[k];
    }
    __syncthreads();

    // decisions + stores: 32 pos x 9 anchors = 288 tasks
    for (int k = 0; k < 2; k++) {
        const int t2 = tid + k * 256;
        if (t2 < NPOS * 9) {
            const int p = t2 / 9, a = t2 % 9;
            const double* v = &vals[p * NOUT];
            const double obj = v[36 + a];
            const double bw2 = v[a * 4 + 2];
            const double bh2 = v[a * 4 + 3];
            const bool keep = (obj > 0.7) && (bw2 > 10.0) && (bh2 > 10.0);
            const int ph = p / TW, pw = p % TW;
            const int hh = h0 + ph, ww = w0 + pw;
            const size_t ob = (((size_t)b * Hn + hh) * Wn + ww) * NOUT;
            #pragma unroll
            for (int j = 0; j < 4; j++)
                out[ob + a * 4 + j] = keep ? (float)v[a * 4 + j] : 0.0f;
            out[ob + 36 + a] = (float)obj;
        }
    }
}

extern "C" void kernel_launch(void* const* d_in, const int* in_sizes, int n_in,
                              void* d_out, int out_size, void* d_ws, size_t ws_size,
                              hipStream_t stream) {
    (void)in_sizes; (void)n_in; (void)d_ws; (void)ws_size; (void)out_size;
    const float* x      = (const float*)d_in[0];
    const float* base_w = (const float*)d_in[1];
    const float* base_b = (const float*)d_in[2];
    const float* cls_w  = (const float*)d_in[3];
    const float* cls_b  = (const float*)d_in[4];
    const float* reg_w  = (const float*)d_in[5];
    const float* reg_b  = (const float*)d_in[6];
    float* out = (float*)d_out;

    const int nblocks = Bn * (Hn / TH) * (Wn / TW);  // 4096
    rpn_fp64_kernel<<<nblocks, 256, 0, stream>>>(
        x, base_w, base_b, cls_w, cls_b, reg_w, reg_b, out);
}

// Round 2
// 5519.577 us; speedup vs baseline: 1.4077x; 1.4077x over previous
//
#include <hip/hip_runtime.h>
#include <math.h>

// RPN head: fp32-VALU conv + fp64 1x1 dots + fp64 borderline refinement.
// B=32 H=64 W=64 C=512 -> feat 256 -> {9 obj logits, 36 reg} -> masked [B,H,W,45]
//
// Mask semantics (obj>0.7 & w>10 & h>10) make any boundary flip an error >=10,
// so: compute everything in fp32 (fast), flag anchors within a wide window of
// any threshold (window >> fp32 noise), recompute flagged positions in fp64.

#define Bn 32
#define Hn 64
#define Wn 64
#define Cn 512
#define Fn 256
#define TH 2
#define TW 16
#define CCn 64            // channels staged per LDS pass
#define NCHUNK (Cn/CCn)   // 8
#define COLS 18           // TW + 2 halo
#define CPADF 20          // row padded to 20 floats (80B, 16B aligned)
#define NPOS (TH*TW)      // 32
#define NOUT 45
#define FPAD 260          // feat row pad (1040B, 16B aligned, breaks 256-stride)

#define LOGIT0 0.8472978603872034  // ln(0.7/0.3)
#define TOL_WH 0.02
#define TOL_LG 0.002

__global__ void zero_counter_kernel(unsigned int* cnt) {
    if (threadIdx.x == 0) cnt[0] = 0;
}

__global__ __launch_bounds__(256, 1) void rpn_fp32_kernel(
    const float* __restrict__ x,
    const float* __restrict__ base_w,
    const float* __restrict__ base_b,
    const float* __restrict__ cls_w,
    const float* __restrict__ cls_b,
    const float* __restrict__ reg_w,
    const float* __restrict__ reg_b,
    float* __restrict__ out,
    unsigned int* __restrict__ flag_cnt,
    unsigned int* __restrict__ flag_list,
    unsigned int flag_cap)
{
    __shared__ __align__(16) char smem_raw[34048];
    float*  xs    = (float*)smem_raw;   // [4][CCn][CPADF] = 20480 B (staging)
    float*  feats = (float*)smem_raw;   // [NPOS][FPAD]    = 33280 B (epilogue)
    double* vals  = (double*)smem_raw;  // [NPOS][NOUT]    = 11520 B (final)

    const int tid = threadIdx.x;
    const int bid = blockIdx.x;
    const int wb = bid & 3;          // 4 w-tiles of 16
    const int hb = (bid >> 2) & 31;  // 32 h-tiles of 2
    const int b  = bid >> 7;         // 32 batches
    const int h0 = hb * TH, w0 = wb * TW;

    float acc0[TW], acc1[TW];
    #pragma unroll
    for (int i = 0; i < TW; i++) { acc0[i] = 0.f; acc1[i] = 0.f; }

    const float* bwp = base_w + tid;  // + (tap*Cn + c)*Fn

    for (int ch = 0; ch < NCHUNK; ch++) {
        const int cbase = ch * CCn;
        __syncthreads();  // protect xs against previous iteration's readers
        // stage 4 rows x 18 cols x 64 ch; float4 global loads, scalar LDS writes
        for (int i = tid; i < 4 * COLS * (CCn / 4); i += 256) {  // 1152 tasks
            const int row = i / (COLS * 16);
            const int rem = i - row * (COLS * 16);
            const int col = rem >> 4;
            const int c4  = (rem & 15) * 4;
            const int y  = h0 + row - 1;
            const int xw = w0 + col - 1;
            float4 v = make_float4(0.f, 0.f, 0.f, 0.f);
            if ((unsigned)y < (unsigned)Hn && (unsigned)xw < (unsigned)Wn)
                v = *(const float4*)&x[(((size_t)b * Hn + y) * Wn + xw) * Cn + cbase + c4];
            xs[((row * CCn + c4 + 0) * CPADF) + col] = v.x;
            xs[((row * CCn + c4 + 1) * CPADF) + col] = v.y;
            xs[((row * CCn + c4 + 2) * CPADF) + col] = v.z;
            xs[((row * CCn + c4 + 3) * CPADF) + col] = v.w;
        }
        __syncthreads();

        #pragma unroll 2
        for (int c = 0; c < CCn; c++) {
            float wv[9];
            #pragma unroll
            for (int t = 0; t < 9; t++)
                wv[t] = bwp[((size_t)t * Cn + cbase + c) * Fn];
            float r[4][COLS];
            #pragma unroll
            for (int row = 0; row < 4; row++) {
                const float* rp = &xs[(row * CCn + c) * CPADF];
                #pragma unroll
                for (int j = 0; j < COLS; j++) r[row][j] = rp[j];
            }
            #pragma unroll
            for (int ky = 0; ky < 3; ky++) {
                #pragma unroll
                for (int kx = 0; kx < 3; kx++) {
                    const float w = wv[ky * 3 + kx];
                    #pragma unroll
                    for (int p = 0; p < TW; p++) {
                        acc0[p] = fmaf(r[ky    ][p + kx], w, acc0[p]);
                        acc1[p] = fmaf(r[ky + 1][p + kx], w, acc1[p]);
                    }
                }
            }
        }
    }

    // bias + relu, scatter feat (channel tid) for all 32 positions into LDS
    const float bias = base_b[tid];
    __syncthreads();
    #pragma unroll
    for (int p = 0; p < TW; p++) {
        float f0 = acc0[p] + bias; if (f0 < 0.f) f0 = 0.f;
        float f1 = acc1[p] + bias; if (f1 < 0.f) f1 = 0.f;
        feats[(0 * TW + p) * FPAD + tid] = f0;
        feats[(1 * TW + p) * FPAD + tid] = f1;
    }
    __syncthreads();

    // 1x1 convs in fp64 on fp32 feats: 1440 length-256 dots. Store RAW logits.
    const int ntask = NPOS * NOUT;  // 1440
    double res[6];
    #pragma unroll
    for (int k = 0; k < 6; k++) res[k] = 0.0;
    for (int k = 0; k < 6; k++) {
        const int task = tid + k * 256;
        if (task < ntask) {
            const int p = task / NOUT, o = task % NOUT;
            const float* wsel;
            int stride;
            double s;
            if (o < 36) { wsel = reg_w + o; stride = 36; s = (double)reg_b[o]; }
            else        { wsel = cls_w + (o - 36); stride = 9; s = (double)cls_b[o - 36]; }
            const float* fp = &feats[p * FPAD];
            double a0 = 0.0, a1 = 0.0, a2 = 0.0, a3 = 0.0;
            for (int t = 0; t < Fn; t += 4) {
                float4 xv = *(const float4*)&fp[t];
                a0 = fma((double)xv.x, (double)wsel[(size_t)(t + 0) * stride], a0);
                a1 = fma((double)xv.y, (double)wsel[(size_t)(t + 1) * stride], a1);
                a2 = fma((double)xv.z, (double)wsel[(size_t)(t + 2) * stride], a2);
                a3 = fma((double)xv.w, (double)wsel[(size_t)(t + 3) * stride], a3);
            }
            res[k] = s + ((a0 + a1) + (a2 + a3));
        }
    }
    __syncthreads();  // all feat reads done; reuse smem for vals
    for (int k = 0; k < 6; k++) {
        const int task = tid + k * 256;
        if (task < ntask) vals[task] = res[k];
    }
    __syncthreads();

    // stores: 32 pos x 9 anchors = 288 tasks (obj slot holds logit -> sigmoid)
    for (int k = 0; k < 2; k++) {
        const int t2 = tid + k * 256;
        if (t2 < NPOS * 9) {
            const int p = t2 / 9, a = t2 % 9;
            const double* v = &vals[p * NOUT];
            const double lg  = v[36 + a];
            const double obj = 1.0 / (1.0 + exp(-lg));
            const double bw2 = v[a * 4 + 2];
            const double bh2 = v[a * 4 + 3];
            const bool keep = (lg > LOGIT0) && (bw2 > 10.0) && (bh2 > 10.0);
            const int ph = p / TW, pw = p % TW;
            const int hh = h0 + ph, ww = w0 + pw;
            const size_t ob = (((size_t)b * Hn + hh) * Wn + ww) * NOUT;
            #pragma unroll
            for (int j = 0; j < 4; j++)
                out[ob + a * 4 + j] = keep ? (float)v[a * 4 + j] : 0.0f;
            out[ob + 36 + a] = (float)obj;
        }
    }

    // borderline flagging: one thread per position
    if (tid < NPOS) {
        const double* v = &vals[tid * NOUT];
        bool flag = false;
        #pragma unroll
        for (int a = 0; a < 9; a++) {
            const double lg  = v[36 + a];
            const double bw2 = v[a * 4 + 2];
            const double bh2 = v[a * 4 + 3];
            flag |= (fabs(bw2 - 10.0) < TOL_WH) | (fabs(bh2 - 10.0) < TOL_WH) |
                    (fabs(lg - LOGIT0) < TOL_LG);
        }
        if (flag && flag_cap > 0) {
            const int ph = tid / TW, pw = tid % TW;
            const unsigned int pos =
                ((unsigned)b << 12) | ((unsigned)(h0 + ph) << 6) | (unsigned)(w0 + pw);
            unsigned int idx = atomicAdd(flag_cnt, 1u);
            if (idx < flag_cap) flag_list[idx] = pos;
        }
    }
}

// fp64 recompute of one position per worklist entry; overwrites its 45 outputs.
__global__ __launch_bounds__(256, 1) void rpn_refine_kernel(
    const float* __restrict__ x,
    const float* __restrict__ base_w,
    const float* __restrict__ base_b,
    const float* __restrict__ cls_w,
    const float* __restrict__ cls_b,
    const float* __restrict__ reg_w,
    const float* __restrict__ reg_b,
    float* __restrict__ out,
    const unsigned int* __restrict__ flag_cnt,
    const unsigned int* __restrict__ flag_list,
    unsigned int flag_cap)
{
    __shared__ __align__(16) float  xp[9 * Cn];   // 18432 B
    __shared__ double featd[Fn];                  //  2048 B
    __shared__ double valsd[NOUT];

    const int tid = threadIdx.x;
    unsigned int count = flag_cnt[0];
    if (count > flag_cap) count = flag_cap;

    for (unsigned int e = blockIdx.x; e < count; e += gridDim.x) {
        const unsigned int pos = flag_list[e];
        const int ww = pos & 63, hh = (pos >> 6) & 63, b = pos >> 12;

        __syncthreads();  // protect xp/featd from previous iteration readers
        for (int i = tid; i < 9 * Cn; i += 256) {
            const int tap = i >> 9, c = i & (Cn - 1);
            const int ky = tap / 3, kx = tap % 3;
            const int y = hh + ky - 1, xw = ww + kx - 1;
            float v = 0.f;
            if ((unsigned)y < (unsigned)Hn && (unsigned)xw < (unsigned)Wn)
                v = x[(((size_t)b * Hn + y) * Wn + xw) * Cn + c];
            xp[i] = v;
        }
        __syncthreads();

        // feat channel tid in fp64: base_w layout is [tap*Cn+c][Fn] = [t][256]
        double a0 = 0.0, a1 = 0.0, a2 = 0.0, a3 = 0.0;
        for (int t = 0; t < 9 * Cn; t += 4) {
            float4 xv = *(const float4*)&xp[t];
            a0 = fma((double)xv.x, (double)base_w[(size_t)(t + 0) * Fn + tid], a0);
            a1 = fma((double)xv.y, (double)base_w[(size_t)(t + 1) * Fn + tid], a1);
            a2 = fma((double)xv.z, (double)base_w[(size_t)(t + 2) * Fn + tid], a2);
            a3 = fma((double)xv.w, (double)base_w[(size_t)(t + 3) * Fn + tid], a3);
        }
        double f = ((a0 + a1) + (a2 + a3)) + (double)base_b[tid];
        if (f < 0.0) f = 0.0;
        featd[tid] = f;
        __syncthreads();

        if (tid < NOUT) {
            const int o = tid;
            const float* wsel;
            int stride;
            double s;
            if (o < 36) { wsel = reg_w + o; stride = 36; s = (double)reg_b[o]; }
            else        { wsel = cls_w + (o - 36); stride = 9; s = (double)cls_b[o - 36]; }
            double acc = 0.0;
            for (int t = 0; t < Fn; t++)
                acc = fma(featd[t], (double)wsel[(size_t)t * stride], acc);
            valsd[o] = s + acc;
        }
        __syncthreads();

        if (tid < 9) {
            const int a = tid;
            const double lg  = valsd[36 + a];
            const double obj = 1.0 / (1.0 + exp(-lg));
            const double bw2 = valsd[a * 4 + 2];
            const double bh2 = valsd[a * 4 + 3];
            const bool keep = (lg > LOGIT0) && (bw2 > 10.0) && (bh2 > 10.0);
            const size_t ob = (((size_t)b * Hn + hh) * Wn + ww) * NOUT;
            #pragma unroll
            for (int j = 0; j < 4; j++)
                out[ob + a * 4 + j] = keep ? (float)valsd[a * 4 + j] : 0.0f;
            out[ob + 36 + a] = (float)obj;
        }
    }
}

extern "C" void kernel_launch(void* const* d_in, const int* in_sizes, int n_in,
                              void* d_out, int out_size, void* d_ws, size_t ws_size,
                              hipStream_t stream) {
    (void)in_sizes; (void)n_in; (void)out_size;
    const float* x      = (const float*)d_in[0];
    const float* base_w = (const float*)d_in[1];
    const float* base_b = (const float*)d_in[2];
    const float* cls_w  = (const float*)d_in[3];
    const float* cls_b  = (const float*)d_in[4];
    const float* reg_w  = (const float*)d_in[5];
    const float* reg_b  = (const float*)d_in[6];
    float* out = (float*)d_out;

    unsigned int* flag_cnt  = (unsigned int*)d_ws;
    unsigned int* flag_list = (unsigned int*)((char*)d_ws + 64);
    unsigned int flag_cap = 0;
    if (ws_size > 128) {
        size_t c = (ws_size - 64) / 4;
        flag_cap = (unsigned int)(c > 131072 ? 131072 : c);
    }

    zero_counter_kernel<<<1, 64, 0, stream>>>(flag_cnt);

    const int nblocks = Bn * (Hn / TH) * (Wn / TW);  // 4096
    rpn_fp32_kernel<<<nblocks, 256, 0, stream>>>(
        x, base_w, base_b, cls_w, cls_b, reg_w, reg_b, out,
        flag_cnt, flag_list, flag_cap);

    rpn_refine_kernel<<<1024, 256, 0, stream>>>(
        x, base_w, base_b, cls_w, cls_b, reg_w, reg_b, out,
        flag_cnt, flag_list, flag_cap);
}

// Round 3
// 1691.102 us; speedup vs baseline: 4.5945x; 3.2639x over previous
//
#include <hip/hip_runtime.h>
#include <math.h>

// RPN head: split-bf16 MFMA conv (3-pass fp32 emulation) + fp32 1x1 +
// fp64 borderline refinement.
// B=32 H=64 W=64 C=512 -> feat 256 -> {9 obj logits, 36 reg} -> masked [B,H,W,45]

typedef __attribute__((ext_vector_type(8)))  short  short8;   // 8 bf16 = 4 VGPRs
typedef __attribute__((ext_vector_type(16))) float  f32x16;   // 32x32 acc

#define Bn 32
#define Hn 64
#define Wn 64
#define Cn 512
#define Fn 256
#define NOUT 45
#define NO 48
#define LOGIT0 0.8472978603872034  // ln(0.7/0.3)
#define TOL_WH 0.02
#define TOL_LG 0.002

// fast-path tiling
#define THs 8
#define TWs 16
#define CC 64
#define NCH 8
#define ROWS 10
#define COLSs 18
#define NCELL (ROWS*COLSs)   // 180
#define KP 72                // padded channel stride (shorts): 144 B, breaks 128B

__device__ __forceinline__ void split_bf16(float f, short& h, short& l) {
    unsigned u  = __float_as_uint(f);
    unsigned hu = (u + 0x7fffu + ((u >> 16) & 1u)) & 0xffff0000u;  // RNE hi
    h = (short)(hu >> 16);
    float lf = f - __uint_as_float(hu);
    unsigned u2 = __float_as_uint(lf);
    l = (short)((u2 + 0x7fffu + ((u2 >> 16) & 1u)) >> 16);          // RNE lo
}

__global__ void zero_counter_kernel(unsigned int* cnt) {
    if (threadIdx.x == 0) cnt[0] = 0;
}

// wcat[t][48]: concat reg_w(36) + cls_w(9) + zero pad; also zero flag counter.
__global__ void prep_misc_kernel(const float* __restrict__ reg_w,
                                 const float* __restrict__ cls_w,
                                 float* __restrict__ wcat,
                                 unsigned int* __restrict__ flag_cnt) {
    if (threadIdx.x == 0 && blockIdx.x == 0) flag_cnt[0] = 0;
    for (int i = threadIdx.x + blockIdx.x * 256; i < 256 * NO; i += 256 * gridDim.x) {
        int t = i / NO, o = i - NO * t;
        float v = 0.f;
        if (o < 36) v = reg_w[t * 36 + o];
        else if (o < NOUT) v = cls_w[t * 9 + (o - 36)];
        wcat[i] = v;
    }
}

// base_w [tap][c][n] fp32 -> w_hi/w_lo [tap][n][c] bf16 (transposed, split)
__global__ __launch_bounds__(256) void wprep_kernel(const float* __restrict__ base_w,
                                                    short* __restrict__ w_hi,
                                                    short* __restrict__ w_lo) {
    __shared__ short th_[64 * 72];
    __shared__ short tl_[64 * 72];
    const int tid = threadIdx.x;
    const int bid = blockIdx.x;            // 288 = 9 taps * 8 c-tiles * 4 n-tiles
    const int tap = bid / 32;
    const int rem = bid - tap * 32;
    const int ct = rem >> 2, nt = rem & 3;
    const int c0 = ct * 64, n0 = nt * 64;
    for (int r4 = 0; r4 < 4; r4++) {
        int cl = r4 * 16 + (tid >> 4);
        int nl = (tid & 15) * 4;
        float4 v = *(const float4*)&base_w[((size_t)tap * Cn + c0 + cl) * Fn + n0 + nl];
        short h, l;
        split_bf16(v.x, h, l); th_[(nl + 0) * 72 + cl] = h; tl_[(nl + 0) * 72 + cl] = l;
        split_bf16(v.y, h, l); th_[(nl + 1) * 72 + cl] = h; tl_[(nl + 1) * 72 + cl] = l;
        split_bf16(v.z, h, l); th_[(nl + 2) * 72 + cl] = h; tl_[(nl + 2) * 72 + cl] = l;
        split_bf16(v.w, h, l); th_[(nl + 3) * 72 + cl] = h; tl_[(nl + 3) * 72 + cl] = l;
    }
    __syncthreads();
    const int nl = tid >> 2, cs = (tid & 3) * 16;
    const size_t ob = ((size_t)tap * Fn + n0 + nl) * Cn + c0 + cs;
    *(short8*)&w_hi[ob]     = *(const short8*)&th_[nl * 72 + cs];
    *(short8*)&w_hi[ob + 8] = *(const short8*)&th_[nl * 72 + cs + 8];
    *(short8*)&w_lo[ob]     = *(const short8*)&tl_[nl * 72 + cs];
    *(short8*)&w_lo[ob + 8] = *(const short8*)&tl_[nl * 72 + cs + 8];
}

__global__ __launch_bounds__(256, 2) void rpn_mfma_kernel(
    const float* __restrict__ x,
    const float* __restrict__ base_b,
    const short* __restrict__ w_hi,   // [9][256][512] bf16
    const short* __restrict__ w_lo,
    const float* __restrict__ wcat,   // [256][48] fp32
    float* __restrict__ out,
    unsigned int* __restrict__ flag_cnt,
    unsigned int* __restrict__ flag_list,
    unsigned int flag_cap)
{
    __shared__ __align__(16) char smem[65536];
    short* xs_hi = (short*)smem;              // [180][72] staging (hi)
    short* xs_lo = xs_hi + NCELL * KP;        // [180][72] staging (lo)
    float* feats = (float*)smem;              // [64][256] swizzled (epilogue)
    float* vals  = (float*)smem;              // [64][48] overlay (final)

    const int tid  = threadIdx.x;
    const int wave = tid >> 6;
    const int lane = tid & 63;
    const int l31  = lane & 31;
    const int l15  = lane & 15;
    const int q5   = lane >> 5;          // 0/1 (k-half selector)
    const int rsel = (lane >> 4) & 1;    // row-within-32 selector for A operand

    const int bid = blockIdx.x;
    const int wb = bid & 3;
    const int hb = (bid >> 2) & 7;
    const int b  = bid >> 5;
    const int h0 = hb * THs, w0 = wb * TWs;

    f32x16 acc[4][2];
    #pragma unroll
    for (int i = 0; i < 4; i++)
        #pragma unroll
        for (int j = 0; j < 2; j++)
            #pragma unroll
            for (int e = 0; e < 16; e++) acc[i][j][e] = 0.f;

    const int n_base = wave * 64;

    for (int ch = 0; ch < NCH; ch++) {
        const int cb = ch * CC;
        __syncthreads();  // previous iteration's LDS readers done
        // stage 10 rows x 18 cols x 64 ch as bf16 hi/lo planes
        for (int r = 0; r < 12; r++) {
            int idx = tid + r * 256;
            if (idx < NCELL * 16) {
                int cell = idx >> 4;
                int c4   = (idx & 15) << 2;
                int row  = cell / COLSs;
                int col  = cell - row * COLSs;
                int y  = h0 + row - 1;
                int xw = w0 + col - 1;
                float4 v = make_float4(0.f, 0.f, 0.f, 0.f);
                if ((unsigned)y < (unsigned)Hn && (unsigned)xw < (unsigned)Wn)
                    v = *(const float4*)&x[(((size_t)b * Hn + y) * Wn + xw) * Cn + cb + c4];
                short ha, la, hbs, lb, hc, lc, hd, ld;
                split_bf16(v.x, ha, la); split_bf16(v.y, hbs, lb);
                split_bf16(v.z, hc, lc); split_bf16(v.w, hd, ld);
                *(short4*)&xs_hi[cell * KP + c4] = make_short4(ha, hbs, hc, hd);
                *(short4*)&xs_lo[cell * KP + c4] = make_short4(la, lb, lc, ld);
            }
        }
        __syncthreads();

        for (int tap = 0; tap < 9; tap++) {
            const int ky = tap / 3, kx = tap - 3 * (tap / 3);
            const short* whb = w_hi + ((size_t)tap * Fn) * Cn + cb;
            const short* wlb = w_lo + ((size_t)tap * Fn) * Cn + cb;
            #pragma unroll
            for (int ks = 0; ks < 4; ks++) {
                const int kl = ks * 16 + q5 * 8;  // this lane's 8-ch K slice
                const short8 bh0 = *(const short8*)(whb + (size_t)(n_base + l31) * Cn + kl);
                const short8 bh1 = *(const short8*)(whb + (size_t)(n_base + 32 + l31) * Cn + kl);
                const short8 bl0 = *(const short8*)(wlb + (size_t)(n_base + l31) * Cn + kl);
                const short8 bl1 = *(const short8*)(wlb + (size_t)(n_base + 32 + l31) * Cn + kl);
                #pragma unroll
                for (int tm = 0; tm < 4; tm++) {
                    const int cell = (tm * 2 + rsel + ky) * COLSs + l15 + kx;
                    const short8 ah = *(const short8*)&xs_hi[cell * KP + kl];
                    const short8 al = *(const short8*)&xs_lo[cell * KP + kl];
                    acc[tm][0] = __builtin_amdgcn_mfma_f32_32x32x16_bf16(ah, bh0, acc[tm][0], 0, 0, 0);
                    acc[tm][1] = __builtin_amdgcn_mfma_f32_32x32x16_bf16(ah, bh1, acc[tm][1], 0, 0, 0);
                    acc[tm][0] = __builtin_amdgcn_mfma_f32_32x32x16_bf16(al, bh0, acc[tm][0], 0, 0, 0);
                    acc[tm][1] = __builtin_amdgcn_mfma_f32_32x32x16_bf16(al, bh1, acc[tm][1], 0, 0, 0);
                    acc[tm][0] = __builtin_amdgcn_mfma_f32_32x32x16_bf16(ah, bl0, acc[tm][0], 0, 0, 0);
                    acc[tm][1] = __builtin_amdgcn_mfma_f32_32x32x16_bf16(ah, bl1, acc[tm][1], 0, 0, 0);
                }
            }
        }
    }

    const float bias0 = base_b[n_base + l31];
    const float bias1 = base_b[n_base + 32 + l31];
    const int og = __builtin_amdgcn_readfirstlane(wave);  // wave-uniform output group
    const int sw_rd = (lane & 7) << 2;

    for (int half = 0; half < 2; half++) {
        __syncthreads();  // conv LDS reads (or prev-half vals reads) done
        // feat -> LDS (XOR-swizzled columns), bias + relu
        #pragma unroll
        for (int tm2 = 0; tm2 < 2; tm2++) {
            const int tm = half * 2 + tm2;
            #pragma unroll
            for (int reg = 0; reg < 16; reg++) {
                const int m_in = (reg & 3) + 8 * (reg >> 2) + 4 * q5;
                const int lm = tm2 * 32 + m_in;      // local position 0..63
                const int swm = (lm & 7) << 2;
                float f0 = acc[tm][0][reg] + bias0; f0 = f0 < 0.f ? 0.f : f0;
                float f1 = acc[tm][1][reg] + bias1; f1 = f1 < 0.f ? 0.f : f1;
                feats[lm * 256 + ((n_base + l31) ^ swm)]      = f0;
                feats[lm * 256 + ((n_base + 32 + l31) ^ swm)] = f1;
            }
        }
        __syncthreads();

        // 1x1 convs: lane = position, wave = 12-output group; raw logits kept
        float res[12];
        #pragma unroll
        for (int j = 0; j < 12; j++) res[j] = 0.f;
        {
            const float* fp  = &feats[lane * 256];
            const float* wb2 = &wcat[og * 12];
            for (int t = 0; t < 256; t += 4) {
                const float4 fv = *(const float4*)&fp[t ^ sw_rd];  // logical t..t+3
                const float* wp = wb2 + (size_t)t * NO;
                #pragma unroll
                for (int u = 0; u < 4; u++) {
                    const float fe = (u == 0) ? fv.x : (u == 1) ? fv.y : (u == 2) ? fv.z : fv.w;
                    const float4 wa = *(const float4*)&wp[u * NO + 0];
                    const float4 wc = *(const float4*)&wp[u * NO + 4];
                    const float4 wd = *(const float4*)&wp[u * NO + 8];
                    res[0] += fe * wa.x; res[1] += fe * wa.y; res[2]  += fe * wa.z; res[3]  += fe * wa.w;
                    res[4] += fe * wc.x; res[5] += fe * wc.y; res[6]  += fe * wc.z; res[7]  += fe * wc.w;
                    res[8] += fe * wd.x; res[9] += fe * wd.y; res[10] += fe * wd.z; res[11] += fe * wd.w;
                }
            }
        }
        __syncthreads();  // all feat reads done; vals overlays feats
        #pragma unroll
        for (int j = 0; j < 12; j++) vals[lane * NO + og * 12 + j] = res[j];
        __syncthreads();

        // stores: 64 pos x 9 anchors
        for (int kq = 0; kq < 3; kq++) {
            int task = tid + kq * 256;
            if (task < 64 * 9) {
                int p = task / 9, a = task - 9 * p;
                const float* v = &vals[p * NO];
                float lg  = v[36 + a];
                float bw  = v[4 * a + 2], bh2 = v[4 * a + 3];
                float obj = 1.f / (1.f + expf(-lg));
                bool keep = ((double)lg > LOGIT0) && (bw > 10.f) && (bh2 > 10.f);
                int rr = p >> 4, cc = p & 15;
                size_t ob = (((size_t)b * Hn + (h0 + half * 4 + rr)) * Wn + (w0 + cc)) * NOUT;
                out[ob + 4 * a + 0] = keep ? v[4 * a + 0] : 0.f;
                out[ob + 4 * a + 1] = keep ? v[4 * a + 1] : 0.f;
                out[ob + 4 * a + 2] = keep ? bw : 0.f;
                out[ob + 4 * a + 3] = keep ? bh2 : 0.f;
                out[ob + 36 + a] = obj;
            }
        }
        // borderline flagging
        if (tid < 64 && flag_cap > 0) {
            const float* v = &vals[tid * NO];
            bool flag = false;
            #pragma unroll
            for (int a = 0; a < 9; a++) {
                float lg = v[36 + a], bw = v[4 * a + 2], bh2 = v[4 * a + 3];
                flag = flag || (fabsf(bw - 10.f) < (float)TOL_WH) ||
                               (fabsf(bh2 - 10.f) < (float)TOL_WH) ||
                               (fabsf(lg - (float)LOGIT0) < (float)TOL_LG);
            }
            if (flag) {
                int rr = tid >> 4, cc = tid & 15;
                unsigned int pos = ((unsigned)b << 12) |
                                   ((unsigned)(h0 + half * 4 + rr) << 6) |
                                   (unsigned)(w0 + cc);
                unsigned int idxf = atomicAdd(flag_cnt, 1u);
                if (idxf < flag_cap) flag_list[idxf] = pos;
            }
        }
    }
}

// fp64 recompute of flagged positions; overwrites their 45 outputs. (validated r1/r2)
__global__ __launch_bounds__(256, 1) void rpn_refine_kernel(
    const float* __restrict__ x,
    const float* __restrict__ base_w,
    const float* __restrict__ base_b,
    const float* __restrict__ cls_w,
    const float* __restrict__ cls_b,
    const float* __restrict__ reg_w,
    const float* __restrict__ reg_b,
    float* __restrict__ out,
    const unsigned int* __restrict__ flag_cnt,
    const unsigned int* __restrict__ flag_list,
    unsigned int flag_cap)
{
    __shared__ __align__(16) float xp[9 * Cn];
    __shared__ double featd[Fn];
    __shared__ double valsd[NOUT];

    const int tid = threadIdx.x;
    unsigned int count = flag_cnt[0];
    if (count > flag_cap) count = flag_cap;

    for (unsigned int e = blockIdx.x; e < count; e += gridDim.x) {
        const unsigned int pos = flag_list[e];
        const int ww = pos & 63, hh = (pos >> 6) & 63, b = pos >> 12;

        __syncthreads();
        for (int i = tid; i < 9 * Cn; i += 256) {
            const int tap = i >> 9, c = i & (Cn - 1);
            const int ky = tap / 3, kx = tap % 3;
            const int y = hh + ky - 1, xw = ww + kx - 1;
            float v = 0.f;
            if ((unsigned)y < (unsigned)Hn && (unsigned)xw < (unsigned)Wn)
                v = x[(((size_t)b * Hn + y) * Wn + xw) * Cn + c];
            xp[i] = v;
        }
        __syncthreads();

        double a0 = 0.0, a1 = 0.0, a2 = 0.0, a3 = 0.0;
        for (int t = 0; t < 9 * Cn; t += 4) {
            float4 xv = *(const float4*)&xp[t];
            a0 = fma((double)xv.x, (double)base_w[(size_t)(t + 0) * Fn + tid], a0);
            a1 = fma((double)xv.y, (double)base_w[(size_t)(t + 1) * Fn + tid], a1);
            a2 = fma((double)xv.z, (double)base_w[(size_t)(t + 2) * Fn + tid], a2);
            a3 = fma((double)xv.w, (double)base_w[(size_t)(t + 3) * Fn + tid], a3);
        }
        double f = ((a0 + a1) + (a2 + a3)) + (double)base_b[tid];
        if (f < 0.0) f = 0.0;
        featd[tid] = f;
        __syncthreads();

        if (tid < NOUT) {
            const int o = tid;
            const float* wsel;
            int stride;
            double s;
            if (o < 36) { wsel = reg_w + o; stride = 36; s = (double)reg_b[o]; }
            else        { wsel = cls_w + (o - 36); stride = 9; s = (double)cls_b[o - 36]; }
            double acc = 0.0;
            for (int t = 0; t < Fn; t++)
                acc = fma(featd[t], (double)wsel[(size_t)t * stride], acc);
            valsd[o] = s + acc;
        }
        __syncthreads();

        if (tid < 9) {
            const int a = tid;
            const double lg  = valsd[36 + a];
            const double obj = 1.0 / (1.0 + exp(-lg));
            const double bw2 = valsd[a * 4 + 2];
            const double bh2 = valsd[a * 4 + 3];
            const bool keep = (lg > LOGIT0) && (bw2 > 10.0) && (bh2 > 10.0);
            const size_t ob = (((size_t)b * Hn + hh) * Wn + ww) * NOUT;
            #pragma unroll
            for (int j = 0; j < 4; j++)
                out[ob + a * 4 + j] = keep ? (float)valsd[a * 4 + j] : 0.0f;
            out[ob + 36 + a] = (float)obj;
        }
    }
}

// ---------- fallback (round-2 proven fp32 path, used only if ws too small) ----------
#define FTH 2
#define FTW 16
#define FCC 64
#define FCOLS 18
#define FCP 20
#define FNP 32
#define FFP 260

__global__ __launch_bounds__(256, 1) void rpn_fp32_fallback_kernel(
    const float* __restrict__ x,
    const float* __restrict__ base_w,
    const float* __restrict__ base_b,
    const float* __restrict__ cls_w,
    const float* __restrict__ cls_b,
    const float* __restrict__ reg_w,
    const float* __restrict__ reg_b,
    float* __restrict__ out,
    unsigned int* __restrict__ flag_cnt,
    unsigned int* __restrict__ flag_list,
    unsigned int flag_cap)
{
    __shared__ __align__(16) char smem_raw[34048];
    float*  xs    = (float*)smem_raw;
    float*  feats = (float*)smem_raw;
    double* vals  = (double*)smem_raw;

    const int tid = threadIdx.x;
    const int bid = blockIdx.x;
    const int wb = bid & 3;
    const int hb = (bid >> 2) & 31;
    const int b  = bid >> 7;
    const int h0 = hb * FTH, w0 = wb * FTW;

    float acc0[FTW], acc1[FTW];
    #pragma unroll
    for (int i = 0; i < FTW; i++) { acc0[i] = 0.f; acc1[i] = 0.f; }
    const float* bwp = base_w + tid;

    for (int ch = 0; ch < 8; ch++) {
        const int cbase = ch * FCC;
        __syncthreads();
        for (int i = tid; i < 4 * FCOLS * (FCC / 4); i += 256) {
            const int row = i / (FCOLS * 16);
            const int rem = i - row * (FCOLS * 16);
            const int col = rem >> 4;
            const int c4  = (rem & 15) * 4;
            const int y  = h0 + row - 1;
            const int xw = w0 + col - 1;
            float4 v = make_float4(0.f, 0.f, 0.f, 0.f);
            if ((unsigned)y < (unsigned)Hn && (unsigned)xw < (unsigned)Wn)
                v = *(const float4*)&x[(((size_t)b * Hn + y) * Wn + xw) * Cn + cbase + c4];
            xs[((row * FCC + c4 + 0) * FCP) + col] = v.x;
            xs[((row * FCC + c4 + 1) * FCP) + col] = v.y;
            xs[((row * FCC + c4 + 2) * FCP) + col] = v.z;
            xs[((row * FCC + c4 + 3) * FCP) + col] = v.w;
        }
        __syncthreads();
        #pragma unroll 2
        for (int c = 0; c < FCC; c++) {
            float wv[9];
            #pragma unroll
            for (int t = 0; t < 9; t++)
                wv[t] = bwp[((size_t)t * Cn + cbase + c) * Fn];
            float rr[4][FCOLS];
            #pragma unroll
            for (int row = 0; row < 4; row++) {
                const float* rp = &xs[(row * FCC + c) * FCP];
                #pragma unroll
                for (int j = 0; j < FCOLS; j++) rr[row][j] = rp[j];
            }
            #pragma unroll
            for (int ky = 0; ky < 3; ky++) {
                #pragma unroll
                for (int kx = 0; kx < 3; kx++) {
                    const float w = wv[ky * 3 + kx];
                    #pragma unroll
                    for (int p = 0; p < FTW; p++) {
                        acc0[p] = fmaf(rr[ky    ][p + kx], w, acc0[p]);
                        acc1[p] = fmaf(rr[ky + 1][p + kx], w, acc1[p]);
                    }
                }
            }
        }
    }

    const float bias = base_b[tid];
    __syncthreads();
    #pragma unroll
    for (int p = 0; p < FTW; p++) {
        float f0 = acc0[p] + bias; if (f0 < 0.f) f0 = 0.f;
        float f1 = acc1[p] + bias; if (f1 < 0.f) f1 = 0.f;
        feats[(0 * FTW + p) * FFP + tid] = f0;
        feats[(1 * FTW + p) * FFP + tid] = f1;
    }
    __syncthreads();

    const int ntask = FNP * NOUT;
    double res[6];
    #pragma unroll
    for (int k = 0; k < 6; k++) res[k] = 0.0;
    for (int k = 0; k < 6; k++) {
        const int task = tid + k * 256;
        if (task < ntask) {
            const int p = task / NOUT, o = task % NOUT;
            const float* wsel;
            int stride;
            double s;
            if (o < 36) { wsel = reg_w + o; stride = 36; s = (double)reg_b[o]; }
            else        { wsel = cls_w + (o - 36); stride = 9; s = (double)cls_b[o - 36]; }
            const float* fp = &feats[p * FFP];
            double a0 = 0.0, a1 = 0.0, a2 = 0.0, a3 = 0.0;
            for (int t = 0; t < Fn; t += 4) {
                float4 xv = *(const float4*)&fp[t];
                a0 = fma((double)xv.x, (double)wsel[(size_t)(t + 0) * stride], a0);
                a1 = fma((double)xv.y, (double)wsel[(size_t)(t + 1) * stride], a1);
                a2 = fma((double)xv.z, (double)wsel[(size_t)(t + 2) * stride], a2);
                a3 = fma((double)xv.w, (double)wsel[(size_t)(t + 3) * stride], a3);
            }
            res[k] = s + ((a0 + a1) + (a2 + a3));
        }
    }
    __syncthreads();
    for (int k = 0; k < 6; k++) {
        const int task = tid + k * 256;
        if (task < ntask) vals[task] = res[k];
    }
    __syncthreads();

    for (int k = 0; k < 2; k++) {
        const int t2 = tid + k * 256;
        if (t2 < FNP * 9) {
            const int p = t2 / 9, a = t2 % 9;
            const double* v = &vals[p * NOUT];
            const double lg  = v[36 + a];
            const double obj = 1.0 / (1.0 + exp(-lg));
            const double bw2 = v[a * 4 + 2];
            const double bh2 = v[a * 4 + 3];
            const bool keep = (lg > LOGIT0) && (bw2 > 10.0) && (bh2 > 10.0);
            const int ph = p / FTW, pw = p % FTW;
            const size_t ob = (((size_t)b * Hn + (h0 + ph)) * Wn + (w0 + pw)) * NOUT;
            #pragma unroll
            for (int j = 0; j < 4; j++)
                out[ob + a * 4 + j] = keep ? (float)v[a * 4 + j] : 0.0f;
            out[ob + 36 + a] = (float)obj;
        }
    }
    if (tid < FNP && flag_cap > 0) {
        const double* v = &vals[tid * NOUT];
        bool flag = false;
        #pragma unroll
        for (int a = 0; a < 9; a++) {
            const double lg  = v[36 + a];
            const double bw2 = v[a * 4 + 2];
            const double bh2 = v[a * 4 + 3];
            flag |= (fabs(bw2 - 10.0) < TOL_WH) | (fabs(bh2 - 10.0) < TOL_WH) |
                    (fabs(lg - LOGIT0) < TOL_LG);
        }
        if (flag) {
            const int ph = tid / FTW, pw = tid % FTW;
            const unsigned int pos =
                ((unsigned)b << 12) | ((unsigned)(h0 + ph) << 6) | (unsigned)(w0 + pw);
            unsigned int idx = atomicAdd(flag_cnt, 1u);
            if (idx < flag_cap) flag_list[idx] = pos;
        }
    }
}

extern "C" void kernel_launch(void* const* d_in, const int* in_sizes, int n_in,
                              void* d_out, int out_size, void* d_ws, size_t ws_size,
                              hipStream_t stream) {
    (void)in_sizes; (void)n_in; (void)out_size;
    const float* x      = (const float*)d_in[0];
    const float* base_w = (const float*)d_in[1];
    const float* base_b = (const float*)d_in[2];
    const float* cls_w  = (const float*)d_in[3];
    const float* cls_b  = (const float*)d_in[4];
    const float* reg_w  = (const float*)d_in[5];
    const float* reg_b  = (const float*)d_in[6];
    float* out = (float*)d_out;

    unsigned int* flag_cnt  = (unsigned int*)d_ws;
    unsigned int* flag_list = (unsigned int*)((char*)d_ws + 64);

    const size_t FLAG_BYTES = 64 + (size_t)65536 * 4;          // 262208
    const size_t WCAT_OFF   = FLAG_BYTES;                      // 262208
    const size_t WHI_OFF    = WCAT_OFF + (size_t)256 * 48 * 4; // 311360
    const size_t WPLANE     = (size_t)9 * 256 * 512 * 2;       // 2359296
    const size_t WLO_OFF    = WHI_OFF + WPLANE;                // 2670656
    const size_t NEED       = WLO_OFF + WPLANE;                // 5029952

    if (ws_size >= NEED) {
        float* wcat = (float*)((char*)d_ws + WCAT_OFF);
        short* w_hi = (short*)((char*)d_ws + WHI_OFF);
        short* w_lo = (short*)((char*)d_ws + WLO_OFF);
        prep_misc_kernel<<<12, 256, 0, stream>>>(reg_w, cls_w, wcat, flag_cnt);
        wprep_kernel<<<288, 256, 0, stream>>>(base_w, w_hi, w_lo);
        rpn_mfma_kernel<<<1024, 256, 0, stream>>>(
            x, base_b, w_hi, w_lo, wcat, out, flag_cnt, flag_list, 65536u);
        rpn_refine_kernel<<<1024, 256, 0, stream>>>(
            x, base_w, base_b, cls_w, cls_b, reg_w, reg_b, out,
            flag_cnt, flag_list, 65536u);
    } else {
        unsigned int flag_cap = 0;
        if (ws_size > 128) {
            size_t c = (ws_size - 64) / 4;
            flag_cap = (unsigned int)(c > 131072 ? 131072 : c);
        }
        zero_counter_kernel<<<1, 64, 0, stream>>>(flag_cnt);
        rpn_fp32_fallback_kernel<<<4096, 256, 0, stream>>>(
            x, base_w, base_b, cls_w, cls_b, reg_w, reg_b, out,
            flag_cnt, flag_list, flag_cap);
        rpn_refine_kernel<<<1024, 256, 0, stream>>>(
            x, base_w, base_b, cls_w, cls_b, reg_w, reg_b, out,
            flag_cnt, flag_list, flag_cap);
    }
}

// Round 4
// 1662.746 us; speedup vs baseline: 4.6728x; 1.0171x over previous
//
#include <hip/hip_runtime.h>
#include <math.h>

// RPN head: split-bf16 MFMA conv (3-term fp32 emulation), conflict-free LDS
// fragment layout, 128-n wave tiles, fused 1x1 + mask epilogue, fp64
// borderline refinement.
// B=32 H=64 W=64 C=512 -> feat 256 -> {9 obj logits, 36 reg} -> masked [B,H,W,45]

typedef __attribute__((ext_vector_type(8)))  short  short8;   // 8 bf16 = 4 VGPRs
typedef __attribute__((ext_vector_type(16))) float  f32x16;   // 32x32 acc

#define Bn 32
#define Hn 64
#define Wn 64
#define Cn 512
#define Fn 256
#define NOUT 45
#define NO 48
#define LOGIT0 0.8472978603872034  // ln(0.7/0.3)
#define TOL_WH 0.008               // 25 sigma of 3-term emulation noise (~3e-4)
#define TOL_LG 0.001

// fast-path tiling
#define THs 8
#define TWs 16
#define CC 64
#define NCH 8
#define ROWS 10
#define COLSs 18
#define NCELL (ROWS*COLSs)    // 180
#define PLANE_S 1448          // shorts per 8-ch plane: 180*8 + 8 pad (724 dwords,
                              // 724%32=20 -> per-plane bank rotation, full cover)

__device__ __forceinline__ void split_bf16(float f, short& h, short& l) {
    unsigned u  = __float_as_uint(f);
    unsigned hu = (u + 0x7fffu + ((u >> 16) & 1u)) & 0xffff0000u;  // RNE hi
    h = (short)(hu >> 16);
    float lf = f - __uint_as_float(hu);
    unsigned u2 = __float_as_uint(lf);
    l = (short)((u2 + 0x7fffu + ((u2 >> 16) & 1u)) >> 16);          // RNE lo
}

__global__ void zero_counter_kernel(unsigned int* cnt) {
    if (threadIdx.x == 0) cnt[0] = 0;
}

// One prep kernel: weight fragment swizzle + wcat + flag-counter zero.
// wf layout: flat entry t = ((tap*8 + jj)*64 + gg)*32 + l31 holds 8 bf16 of
// w[n = jj*32+l31][c = gg*8 .. +7]  ->  main-kernel B-load is lane-contiguous.
__global__ __launch_bounds__(256) void wprep2_kernel(
    const float* __restrict__ base_w,
    const float* __restrict__ reg_w,
    const float* __restrict__ cls_w,
    short* __restrict__ wf_hi,
    short* __restrict__ wf_lo,
    float* __restrict__ wcat,
    unsigned int* __restrict__ flag_cnt)
{
    if (blockIdx.x == 576) {  // misc block
        if (threadIdx.x == 0) flag_cnt[0] = 0;
        for (int i = threadIdx.x; i < 256 * NO; i += 256) {
            int t = i / NO, o = i - NO * t;
            float v = 0.f;
            if (o < 36) v = reg_w[t * 36 + o];
            else if (o < NOUT) v = cls_w[t * 9 + (o - 36)];
            wcat[i] = v;
        }
        return;
    }
    const int t = blockIdx.x * 256 + threadIdx.x;   // 0 .. 147455
    const int l31 = t & 31;
    const int gg  = (t >> 5) & 63;
    const int jj  = (t >> 11) & 7;
    const int tap = t >> 14;
    const int n  = jj * 32 + l31;
    const int c0 = gg * 8;
    short h[8], l[8];
    #pragma unroll
    for (int u = 0; u < 8; u++)
        split_bf16(base_w[((size_t)(tap * Cn + c0 + u)) * Fn + n], h[u], l[u]);
    short8 vh = { h[0], h[1], h[2], h[3], h[4], h[5], h[6], h[7] };
    short8 vl = { l[0], l[1], l[2], l[3], l[4], l[5], l[6], l[7] };
    *(short8*)&wf_hi[(size_t)t * 8] = vh;
    *(short8*)&wf_lo[(size_t)t * 8] = vl;
}

__global__ __launch_bounds__(256, 2) void rpn_mfma2_kernel(
    const float* __restrict__ x,
    const float* __restrict__ base_b,
    const short* __restrict__ wf_hi,
    const short* __restrict__ wf_lo,
    const float* __restrict__ wcat,   // [256][48] fp32
    float* __restrict__ out,
    unsigned int* __restrict__ flag_cnt,
    unsigned int* __restrict__ flag_list,
    unsigned int flag_cap)
{
    __shared__ __align__(16) char smem[65536];
    short* xs_hi = (short*)smem;                  // 8 planes * 1448 = 23168 B
    short* xs_lo = xs_hi + 8 * PLANE_S;           // + 23168 B (total 46336)
    float* feats = (float*)smem;                  // [64][256] swizzled (epilogue)
    float* vals  = (float*)smem;                  // [64][48] overlay (final)

    const int tid  = threadIdx.x;
    const int wave = tid >> 6;
    const int lane = tid & 63;
    const int l31  = lane & 31;
    const int l15  = lane & 15;
    const int q5   = lane >> 5;          // k-half selector (A and B)
    const int rsel = (lane >> 4) & 1;    // row-within-m-block selector
    const int wq   = wave >> 1;          // position half (rows 4wq..4wq+3)
    const int wn   = wave & 1;           // n half (n = 128*wn ..)

    const int bid = blockIdx.x;
    const int wb = bid & 3;
    const int hb = (bid >> 2) & 7;
    const int b  = bid >> 5;
    const int h0 = hb * THs, w0 = wb * TWs;

    f32x16 acc[2][4];
    #pragma unroll
    for (int i = 0; i < 2; i++)
        #pragma unroll
        for (int j = 0; j < 4; j++)
            #pragma unroll
            for (int e = 0; e < 16; e++) acc[i][j][e] = 0.f;

    for (int ch = 0; ch < NCH; ch++) {
        const int cb = ch * CC;
        __syncthreads();  // previous iteration's LDS readers done
        // stage 180 cells x 64 ch as 8-channel-group fragment planes
        for (int r = 0; r < 12; r++) {
            int idx = tid + r * 256;
            if (idx < NCELL * 16) {
                int cell = idx >> 4;
                int c4   = (idx & 15) << 2;
                int row  = cell / COLSs;
                int col  = cell - row * COLSs;
                int y  = h0 + row - 1;
                int xw = w0 + col - 1;
                float4 v = make_float4(0.f, 0.f, 0.f, 0.f);
                if ((unsigned)y < (unsigned)Hn && (unsigned)xw < (unsigned)Wn)
                    v = *(const float4*)&x[(((size_t)b * Hn + y) * Wn + xw) * Cn + cb + c4];
                short ha, la, hb2, lb, hc, lc, hd, ld;
                split_bf16(v.x, ha, la); split_bf16(v.y, hb2, lb);
                split_bf16(v.z, hc, lc); split_bf16(v.w, hd, ld);
                const int o = (c4 >> 3) * PLANE_S + cell * 8 + (c4 & 7);
                *(short4*)&xs_hi[o] = make_short4(ha, hb2, hc, hd);
                *(short4*)&xs_lo[o] = make_short4(la, lb, lc, ld);
            }
        }
        __syncthreads();

        for (int tap = 0; tap < 9; tap++) {
            const int ky = tap / 3, kx = tap - 3 * (tap / 3);
            const int arow0 = (wq * 4 + rsel + ky) * 144 + (l15 + kx) * 8;
            for (int ks = 0; ks < 4; ks++) {
                const int ap = (ks * 2 + q5) * PLANE_S + arow0;
                const size_t wrow =
                    ((size_t)(tap * 8 + wn * 4) * 2048 + (ch * 8 + ks * 2) * 32 + lane) * 8;
                short8 bh[4];
                #pragma unroll
                for (int j = 0; j < 4; j++)
                    bh[j] = *(const short8*)(wf_hi + wrow + (size_t)j * 16384);
                const short8 ah0 = *(const short8*)&xs_hi[ap];
                const short8 al0 = *(const short8*)&xs_lo[ap];
                const short8 ah1 = *(const short8*)&xs_hi[ap + 288];
                const short8 al1 = *(const short8*)&xs_lo[ap + 288];
                #pragma unroll
                for (int j = 0; j < 4; j++) {
                    acc[0][j] = __builtin_amdgcn_mfma_f32_32x32x16_bf16(ah0, bh[j], acc[0][j], 0, 0, 0);
                    acc[1][j] = __builtin_amdgcn_mfma_f32_32x32x16_bf16(ah1, bh[j], acc[1][j], 0, 0, 0);
                }
                #pragma unroll
                for (int j = 0; j < 4; j++) {
                    acc[0][j] = __builtin_amdgcn_mfma_f32_32x32x16_bf16(al0, bh[j], acc[0][j], 0, 0, 0);
                    acc[1][j] = __builtin_amdgcn_mfma_f32_32x32x16_bf16(al1, bh[j], acc[1][j], 0, 0, 0);
                }
                short8 bl[4];
                #pragma unroll
                for (int j = 0; j < 4; j++)
                    bl[j] = *(const short8*)(wf_lo + wrow + (size_t)j * 16384);
                #pragma unroll
                for (int j = 0; j < 4; j++) {
                    acc[0][j] = __builtin_amdgcn_mfma_f32_32x32x16_bf16(ah0, bl[j], acc[0][j], 0, 0, 0);
                    acc[1][j] = __builtin_amdgcn_mfma_f32_32x32x16_bf16(ah1, bl[j], acc[1][j], 0, 0, 0);
                }
            }
        }
    }

    float bias[4];
    #pragma unroll
    for (int j = 0; j < 4; j++) bias[j] = base_b[wn * 128 + 32 * j + l31];
    const int og = __builtin_amdgcn_readfirstlane(wave);  // wave-uniform out group
    const int sw_rd = (lane & 7) << 2;

    for (int half = 0; half < 2; half++) {
        __syncthreads();  // conv LDS reads (or prev-half vals reads) done
        if (wq == half) {
            #pragma unroll
            for (int tml = 0; tml < 2; tml++) {
                #pragma unroll
                for (int reg = 0; reg < 16; reg++) {
                    const int m_in = (reg & 3) + 8 * (reg >> 2) + 4 * q5;
                    const int lm = tml * 32 + m_in;
                    const int swm = (lm & 7) << 2;
                    #pragma unroll
                    for (int j = 0; j < 4; j++) {
                        const int n = wn * 128 + 32 * j + l31;
                        float f = acc[tml][j][reg] + bias[j];
                        f = f < 0.f ? 0.f : f;
                        feats[lm * 256 + (n ^ swm)] = f;
                    }
                }
            }
        }
        __syncthreads();

        // 1x1 convs: lane = position, wave = 12-output group; raw logits kept
        float res[12];
        #pragma unroll
        for (int j = 0; j < 12; j++) res[j] = 0.f;
        {
            const float* fp  = &feats[lane * 256];
            const float* wb2 = &wcat[og * 12];
            for (int t = 0; t < 256; t += 4) {
                const float4 fv = *(const float4*)&fp[t ^ sw_rd];  // logical t..t+3
                const float* wp = wb2 + (size_t)t * NO;
                #pragma unroll
                for (int u = 0; u < 4; u++) {
                    const float fe = (u == 0) ? fv.x : (u == 1) ? fv.y : (u == 2) ? fv.z : fv.w;
                    const float4 wa = *(const float4*)&wp[u * NO + 0];
                    const float4 wc = *(const float4*)&wp[u * NO + 4];
                    const float4 wd = *(const float4*)&wp[u * NO + 8];
                    res[0] += fe * wa.x; res[1] += fe * wa.y; res[2]  += fe * wa.z; res[3]  += fe * wa.w;
                    res[4] += fe * wc.x; res[5] += fe * wc.y; res[6]  += fe * wc.z; res[7]  += fe * wc.w;
                    res[8] += fe * wd.x; res[9] += fe * wd.y; res[10] += fe * wd.z; res[11] += fe * wd.w;
                }
            }
        }
        __syncthreads();  // all feat reads done; vals overlays feats
        #pragma unroll
        for (int j = 0; j < 12; j++) vals[lane * NO + og * 12 + j] = res[j];
        __syncthreads();

        // stores: 64 pos x 9 anchors
        for (int kq = 0; kq < 3; kq++) {
            int task = tid + kq * 256;
            if (task < 64 * 9) {
                int p = task / 9, a = task - 9 * p;
                const float* v = &vals[p * NO];
                float lg  = v[36 + a];
                float bw  = v[4 * a + 2], bh2 = v[4 * a + 3];
                float obj = 1.f / (1.f + expf(-lg));
                bool keep = ((double)lg > LOGIT0) && (bw > 10.f) && (bh2 > 10.f);
                int rr = p >> 4, cc = p & 15;
                size_t ob = (((size_t)b * Hn + (h0 + half * 4 + rr)) * Wn + (w0 + cc)) * NOUT;
                out[ob + 4 * a + 0] = keep ? v[4 * a + 0] : 0.f;
                out[ob + 4 * a + 1] = keep ? v[4 * a + 1] : 0.f;
                out[ob + 4 * a + 2] = keep ? bw : 0.f;
                out[ob + 4 * a + 3] = keep ? bh2 : 0.f;
                out[ob + 36 + a] = obj;
            }
        }
        // borderline flagging
        if (tid < 64 && flag_cap > 0) {
            const float* v = &vals[tid * NO];
            bool flag = false;
            #pragma unroll
            for (int a = 0; a < 9; a++) {
                float lg = v[36 + a], bw = v[4 * a + 2], bh2 = v[4 * a + 3];
                flag = flag || (fabsf(bw - 10.f) < (float)TOL_WH) ||
                               (fabsf(bh2 - 10.f) < (float)TOL_WH) ||
                               (fabsf(lg - (float)LOGIT0) < (float)TOL_LG);
            }
            if (flag) {
                int rr = tid >> 4, cc = tid & 15;
                unsigned int pos = ((unsigned)b << 12) |
                                   ((unsigned)(h0 + half * 4 + rr) << 6) |
                                   (unsigned)(w0 + cc);
                unsigned int idxf = atomicAdd(flag_cnt, 1u);
                if (idxf < flag_cap) flag_list[idxf] = pos;
            }
        }
    }
}

// fp64 recompute of flagged positions; overwrites their 45 outputs. (validated r1-r3)
__global__ __launch_bounds__(256, 1) void rpn_refine_kernel(
    const float* __restrict__ x,
    const float* __restrict__ base_w,
    const float* __restrict__ base_b,
    const float* __restrict__ cls_w,
    const float* __restrict__ cls_b,
    const float* __restrict__ reg_w,
    const float* __restrict__ reg_b,
    float* __restrict__ out,
    const unsigned int* __restrict__ flag_cnt,
    const unsigned int* __restrict__ flag_list,
    unsigned int flag_cap)
{
    __shared__ __align__(16) float xp[9 * Cn];
    __shared__ double featd[Fn];
    __shared__ double valsd[NOUT];

    const int tid = threadIdx.x;
    unsigned int count = flag_cnt[0];
    if (count > flag_cap) count = flag_cap;

    for (unsigned int e = blockIdx.x; e < count; e += gridDim.x) {
        const unsigned int pos = flag_list[e];
        const int ww = pos & 63, hh = (pos >> 6) & 63, b = pos >> 12;

        __syncthreads();
        for (int i = tid; i < 9 * Cn; i += 256) {
            const int tap = i >> 9, c = i & (Cn - 1);
            const int ky = tap / 3, kx = tap % 3;
            const int y = hh + ky - 1, xw = ww + kx - 1;
            float v = 0.f;
            if ((unsigned)y < (unsigned)Hn && (unsigned)xw < (unsigned)Wn)
                v = x[(((size_t)b * Hn + y) * Wn + xw) * Cn + c];
            xp[i] = v;
        }
        __syncthreads();

        double a0 = 0.0, a1 = 0.0, a2 = 0.0, a3 = 0.0;
        for (int t = 0; t < 9 * Cn; t += 4) {
            float4 xv = *(const float4*)&xp[t];
            a0 = fma((double)xv.x, (double)base_w[(size_t)(t + 0) * Fn + tid], a0);
            a1 = fma((double)xv.y, (double)base_w[(size_t)(t + 1) * Fn + tid], a1);
            a2 = fma((double)xv.z, (double)base_w[(size_t)(t + 2) * Fn + tid], a2);
            a3 = fma((double)xv.w, (double)base_w[(size_t)(t + 3) * Fn + tid], a3);
        }
        double f = ((a0 + a1) + (a2 + a3)) + (double)base_b[tid];
        if (f < 0.0) f = 0.0;
        featd[tid] = f;
        __syncthreads();

        if (tid < NOUT) {
            const int o = tid;
            const float* wsel;
            int stride;
            double s;
            if (o < 36) { wsel = reg_w + o; stride = 36; s = (double)reg_b[o]; }
            else        { wsel = cls_w + (o - 36); stride = 9; s = (double)cls_b[o - 36]; }
            double acc = 0.0;
            for (int t = 0; t < Fn; t++)
                acc = fma(featd[t], (double)wsel[(size_t)t * stride], acc);
            valsd[o] = s + acc;
        }
        __syncthreads();

        if (tid < 9) {
            const int a = tid;
            const double lg  = valsd[36 + a];
            const double obj = 1.0 / (1.0 + exp(-lg));
            const double bw2 = valsd[a * 4 + 2];
            const double bh2 = valsd[a * 4 + 3];
            const bool keep = (lg > LOGIT0) && (bw2 > 10.0) && (bh2 > 10.0);
            const size_t ob = (((size_t)b * Hn + hh) * Wn + ww) * NOUT;
            #pragma unroll
            for (int j = 0; j < 4; j++)
                out[ob + a * 4 + j] = keep ? (float)valsd[a * 4 + j] : 0.0f;
            out[ob + 36 + a] = (float)obj;
        }
    }
}

// ---------- fallback (round-2 proven fp32 path, used only if ws too small) ----------
#define FTH 2
#define FTW 16
#define FCC 64
#define FCOLS 18
#define FCP 20
#define FNP 32
#define FFP 260

__global__ __launch_bounds__(256, 1) void rpn_fp32_fallback_kernel(
    const float* __restrict__ x,
    const float* __restrict__ base_w,
    const float* __restrict__ base_b,
    const float* __restrict__ cls_w,
    const float* __restrict__ cls_b,
    const float* __restrict__ reg_w,
    const float* __restrict__ reg_b,
    float* __restrict__ out,
    unsigned int* __restrict__ flag_cnt,
    unsigned int* __restrict__ flag_list,
    unsigned int flag_cap)
{
    __shared__ __align__(16) char smem_raw[34048];
    float*  xs    = (float*)smem_raw;
    float*  feats = (float*)smem_raw;
    double* vals  = (double*)smem_raw;

    const int tid = threadIdx.x;
    const int bid = blockIdx.x;
    const int wb = bid & 3;
    const int hb = (bid >> 2) & 31;
    const int b  = bid >> 7;
    const int h0 = hb * FTH, w0 = wb * FTW;

    float acc0[FTW], acc1[FTW];
    #pragma unroll
    for (int i = 0; i < FTW; i++) { acc0[i] = 0.f; acc1[i] = 0.f; }
    const float* bwp = base_w + tid;

    for (int ch = 0; ch < 8; ch++) {
        const int cbase = ch * FCC;
        __syncthreads();
        for (int i = tid; i < 4 * FCOLS * (FCC / 4); i += 256) {
            const int row = i / (FCOLS * 16);
            const int rem = i - row * (FCOLS * 16);
            const int col = rem >> 4;
            const int c4  = (rem & 15) * 4;
            const int y  = h0 + row - 1;
            const int xw = w0 + col - 1;
            float4 v = make_float4(0.f, 0.f, 0.f, 0.f);
            if ((unsigned)y < (unsigned)Hn && (unsigned)xw < (unsigned)Wn)
                v = *(const float4*)&x[(((size_t)b * Hn + y) * Wn + xw) * Cn + cbase + c4];
            xs[((row * FCC + c4 + 0) * FCP) + col] = v.x;
            xs[((row * FCC + c4 + 1) * FCP) + col] = v.y;
            xs[((row * FCC + c4 + 2) * FCP) + col] = v.z;
            xs[((row * FCC + c4 + 3) * FCP) + col] = v.w;
        }
        __syncthreads();
        #pragma unroll 2
        for (int c = 0; c < FCC; c++) {
            float wv[9];
            #pragma unroll
            for (int t = 0; t < 9; t++)
                wv[t] = bwp[((size_t)t * Cn + cbase + c) * Fn];
            float rr[4][FCOLS];
            #pragma unroll
            for (int row = 0; row < 4; row++) {
                const float* rp = &xs[(row * FCC + c) * FCP];
                #pragma unroll
                for (int j = 0; j < FCOLS; j++) rr[row][j] = rp[j];
            }
            #pragma unroll
            for (int ky = 0; ky < 3; ky++) {
                #pragma unroll
                for (int kx = 0; kx < 3; kx++) {
                    const float w = wv[ky * 3 + kx];
                    #pragma unroll
                    for (int p = 0; p < FTW; p++) {
                        acc0[p] = fmaf(rr[ky    ][p + kx], w, acc0[p]);
                        acc1[p] = fmaf(rr[ky + 1][p + kx], w, acc1[p]);
                    }
                }
            }
        }
    }

    const float bias = base_b[tid];
    __syncthreads();
    #pragma unroll
    for (int p = 0; p < FTW; p++) {
        float f0 = acc0[p] + bias; if (f0 < 0.f) f0 = 0.f;
        float f1 = acc1[p] + bias; if (f1 < 0.f) f1 = 0.f;
        feats[(0 * FTW + p) * FFP + tid] = f0;
        feats[(1 * FTW + p) * FFP + tid] = f1;
    }
    __syncthreads();

    const int ntask = FNP * NOUT;
    double res[6];
    #pragma unroll
    for (int k = 0; k < 6; k++) res[k] = 0.0;
    for (int k = 0; k < 6; k++) {
        const int task = tid + k * 256;
        if (task < ntask) {
            const int p = task / NOUT, o = task % NOUT;
            const float* wsel;
            int stride;
            double s;
            if (o < 36) { wsel = reg_w + o; stride = 36; s = (double)reg_b[o]; }
            else        { wsel = cls_w + (o - 36); stride = 9; s = (double)cls_b[o - 36]; }
            const float* fp = &feats[p * FFP];
            double a0 = 0.0, a1 = 0.0, a2 = 0.0, a3 = 0.0;
            for (int t = 0; t < Fn; t += 4) {
                float4 xv = *(const float4*)&fp[t];
                a0 = fma((double)xv.x, (double)wsel[(size_t)(t + 0) * stride], a0);
                a1 = fma((double)xv.y, (double)wsel[(size_t)(t + 1) * stride], a1);
                a2 = fma((double)xv.z, (double)wsel[(size_t)(t + 2) * stride], a2);
                a3 = fma((double)xv.w, (double)wsel[(size_t)(t + 3) * stride], a3);
            }
            res[k] = s + ((a0 + a1) + (a2 + a3));
        }
    }
    __syncthreads();
    for (int k = 0; k < 6; k++) {
        const int task = tid + k * 256;
        if (task < ntask) vals[task] = res[k];
    }
    __syncthreads();

    for (int k = 0; k < 2; k++) {
        const int t2 = tid + k * 256;
        if (t2 < FNP * 9) {
            const int p = t2 / 9, a = t2 % 9;
            const double* v = &vals[p * NOUT];
            const double lg  = v[36 + a];
            const double obj = 1.0 / (1.0 + exp(-lg));
            const double bw2 = v[a * 4 + 2];
            const double bh2 = v[a * 4 + 3];
            const bool keep = (lg > LOGIT0) && (bw2 > 10.0) && (bh2 > 10.0);
            const int ph = p / FTW, pw = p % FTW;
            const size_t ob = (((size_t)b * Hn + (h0 + ph)) * Wn + (w0 + pw)) * NOUT;
            #pragma unroll
            for (int j = 0; j < 4; j++)
                out[ob + a * 4 + j] = keep ? (float)v[a * 4 + j] : 0.0f;
            out[ob + 36 + a] = (float)obj;
        }
    }
    if (tid < FNP && flag_cap > 0) {
        const double* v = &vals[tid * NOUT];
        bool flag = false;
        #pragma unroll
        for (int a = 0; a < 9; a++) {
            const double lg  = v[36 + a];
            const double bw2 = v[a * 4 + 2];
            const double bh2 = v[a * 4 + 3];
            flag |= (fabs(bw2 - 10.0) < 0.02) | (fabs(bh2 - 10.0) < 0.02) |
                    (fabs(lg - LOGIT0) < 0.002);
        }
        if (flag) {
            const int ph = tid / FTW, pw = tid % FTW;
            const unsigned int pos =
                ((unsigned)b << 12) | ((unsigned)(h0 + ph) << 6) | (unsigned)(w0 + pw);
            unsigned int idx = atomicAdd(flag_cnt, 1u);
            if (idx < flag_cap) flag_list[idx] = pos;
        }
    }
}

extern "C" void kernel_launch(void* const* d_in, const int* in_sizes, int n_in,
                              void* d_out, int out_size, void* d_ws, size_t ws_size,
                              hipStream_t stream) {
    (void)in_sizes; (void)n_in; (void)out_size;
    const float* x      = (const float*)d_in[0];
    const float* base_w = (const float*)d_in[1];
    const float* base_b = (const float*)d_in[2];
    const float* cls_w  = (const float*)d_in[3];
    const float* cls_b  = (const float*)d_in[4];
    const float* reg_w  = (const float*)d_in[5];
    const float* reg_b  = (const float*)d_in[6];
    float* out = (float*)d_out;

    unsigned int* flag_cnt  = (unsigned int*)d_ws;
    unsigned int* flag_list = (unsigned int*)((char*)d_ws + 64);

    const size_t FLAG_BYTES = 64 + (size_t)65536 * 4;          // 262208
    const size_t WCAT_OFF   = FLAG_BYTES;                      // 262208
    const size_t WHI_OFF    = WCAT_OFF + (size_t)256 * 48 * 4; // 311360
    const size_t WPLANE     = (size_t)9 * 256 * 512 * 2;       // 2359296
    const size_t WLO_OFF    = WHI_OFF + WPLANE;
    const size_t NEED       = WLO_OFF + WPLANE;                // ~5.03 MB

    if (ws_size >= NEED) {
        float* wcat = (float*)((char*)d_ws + WCAT_OFF);
        short* wf_hi = (short*)((char*)d_ws + WHI_OFF);
        short* wf_lo = (short*)((char*)d_ws + WLO_OFF);
        wprep2_kernel<<<577, 256, 0, stream>>>(base_w, reg_w, cls_w,
                                               wf_hi, wf_lo, wcat, flag_cnt);
        rpn_mfma2_kernel<<<1024, 256, 0, stream>>>(
            x, base_b, wf_hi, wf_lo, wcat, out, flag_cnt, flag_list, 65536u);
        rpn_refine_kernel<<<512, 256, 0, stream>>>(
            x, base_w, base_b, cls_w, cls_b, reg_w, reg_b, out,
            flag_cnt, flag_list, 65536u);
    } else {
        unsigned int flag_cap = 0;
        if (ws_size > 128) {
            size_t c = (ws_size - 64) / 4;
            flag_cap = (unsigned int)(c > 131072 ? 131072 : c);
        }
        zero_counter_kernel<<<1, 64, 0, stream>>>(flag_cnt);
        rpn_fp32_fallback_kernel<<<4096, 256, 0, stream>>>(
            x, base_w, base_b, cls_w, cls_b, reg_w, reg_b, out,
            flag_cnt, flag_list, flag_cap);
        rpn_refine_kernel<<<512, 256, 0, stream>>>(
            x, base_w, base_b, cls_w, cls_b, reg_w, reg_b, out,
            flag_cnt, flag_list, flag_cap);
    }
}